// Round 1
// baseline (1447.565 us; speedup 1.0000x reference)
//
#include <hip/hip_runtime.h>
#include <hip/hip_bf16.h>

#define Bn 16
#define Tn 4096
#define IN_DIM 64
#define L 256
#define NL 10
#define PADROWS 512
#define TP (Tn + PADROWS)   // 4608
#define COLS 64

typedef __attribute__((ext_vector_type(8))) short short8;
typedef __attribute__((ext_vector_type(4))) float f32x4;
typedef unsigned short ushort_t;
typedef unsigned int uint_t;

__device__ inline ushort_t f2bf(float f) {
    uint_t u = __builtin_bit_cast(uint_t, f);
    u = u + 0x7fffu + ((u >> 16) & 1u);
    return (ushort_t)(u >> 16);
}

__device__ inline float fexp2f(float x) { return __builtin_amdgcn_exp2f(x); }
__device__ inline float frcpf(float x)  { return __builtin_amdgcn_rcpf(x); }
__device__ inline float tanh_fast(float x) {
    float e = fexp2f(x * 2.8853900817779268f);   // e^(2x)
    return 1.f - 2.f * frcpf(e + 1.f);
}
__device__ inline float sigm_fast(float x) {
    return frcpf(1.f + fexp2f(-1.4426950408889634f * x));
}

__device__ inline f32x4 mfma16(short8 a, short8 b, f32x4 c) {
    return __builtin_amdgcn_mfma_f32_16x16x32_bf16(a, b, c, 0, 0, 0);
}

__device__ inline void gld_lds16(const void* src, void* dst) {
    __builtin_amdgcn_global_load_lds(
        (const __attribute__((address_space(1))) void*)src,
        (__attribute__((address_space(3))) void*)dst, 16, 0, 0);
}

// ---------------------------------------------------------------------------
// prep: fp32 weights -> bf16 (with filt/gate k=2 tap concat), zero h pads
// ---------------------------------------------------------------------------
__global__ void prep_kernel(
    const float* __restrict__ filt_w, const float* __restrict__ gate_w,
    const float* __restrict__ res_w,  const float* __restrict__ skip_w,
    const float* __restrict__ emb_w,  const float* __restrict__ fin1_w,
    const float* __restrict__ fin2_w, const float* __restrict__ out_w,
    ushort_t* __restrict__ Wf, ushort_t* __restrict__ Wg,
    ushort_t* __restrict__ Wr, ushort_t* __restrict__ Ws,
    ushort_t* __restrict__ We, ushort_t* __restrict__ W1,
    ushort_t* __restrict__ W2, ushort_t* __restrict__ Wo,
    ushort_t* __restrict__ h_a, ushort_t* __restrict__ h_b)
{
    const int stride = gridDim.x * blockDim.x;
    const int tid0 = blockIdx.x * blockDim.x + threadIdx.x;

    // filt/gate: Wcat[i][o][k]: k<256 -> tap1 (unshifted), k>=256 -> tap0 (shifted)
    for (int idx = tid0; idx < NL * L * 2 * L; idx += stride) {
        int k = idx & 511;
        int o = (idx >> 9) & 255;
        int i = idx >> 17;
        int tap = (k < 256) ? 1 : 0;
        int kk = k & 255;
        int src = ((i * 256 + o) * 256 + kk) * 2 + tap;
        Wf[idx] = f2bf(filt_w[src]);
        Wg[idx] = f2bf(gate_w[src]);
    }
    for (int idx = tid0; idx < NL * L * L; idx += stride)        Wr[idx] = f2bf(res_w[idx]);
    for (int idx = tid0; idx < (NL + 1) * L * L; idx += stride)  Ws[idx] = f2bf(skip_w[idx]);
    for (int idx = tid0; idx < L * IN_DIM; idx += stride)        We[idx] = f2bf(emb_w[idx]);
    for (int idx = tid0; idx < L * L; idx += stride) {
        W1[idx] = f2bf(fin1_w[idx]);
        W2[idx] = f2bf(fin2_w[idx]);
    }
    for (int idx = tid0; idx < 64 * L; idx += stride)            Wo[idx] = f2bf(out_w[idx]);
    // zero the 512-row time pads of both h buffers (front of each batch slab)
    for (int idx = tid0; idx < Bn * PADROWS * L; idx += stride) {
        int bb = idx >> 17;            // 512*256 = 1<<17
        int r = idx & 131071;
        size_t off = (size_t)bb * TP * L + r;
        h_a[off] = 0;
        h_b[off] = 0;
    }
}

// ---------------------------------------------------------------------------
// embedding: h0 = relu(We @ x^T + eb); final = Ws0 @ h0 + sb0
// ---------------------------------------------------------------------------
__global__ __launch_bounds__(512, 1) void emb_kernel(
    const float* __restrict__ x,
    const ushort_t* __restrict__ We, const float* __restrict__ eb,
    const ushort_t* __restrict__ Ws0, const float* __restrict__ sb0,
    ushort_t* __restrict__ h_out, float* __restrict__ fin)
{
    __shared__ __align__(16) char gt[32 * 1024];   // [64][256] bf16, swizzled

    const int tid = threadIdx.x;
    const int w = tid >> 6;
    const int ln = tid & 63;
    const int q = ln >> 4;
    const int n16 = ln & 15;
    const int blk = blockIdx.x;
    const int b = blk >> 6;
    const int t0 = (blk & 63) * COLS;
    const int row0 = w * 32;

    f32x4 acc[2][4];
    #pragma unroll
    for (int rt = 0; rt < 2; ++rt)
        #pragma unroll
        for (int ct = 0; ct < 4; ++ct) acc[rt][ct] = (f32x4){0.f, 0.f, 0.f, 0.f};

    #pragma unroll
    for (int ks = 0; ks < 2; ++ks) {
        const int k = ks * 32 + q * 8;
        short8 bfr[4];
        #pragma unroll
        for (int ct = 0; ct < 4; ++ct) {
            int c = ct * 16 + n16;
            const float* xp = x + ((size_t)(b * Tn + t0 + c)) * IN_DIM + k;
            f32x4 x0 = *(const f32x4*)xp;
            f32x4 x1 = *(const f32x4*)(xp + 4);
            short8 v;
            v[0] = (short)f2bf(x0[0]); v[1] = (short)f2bf(x0[1]);
            v[2] = (short)f2bf(x0[2]); v[3] = (short)f2bf(x0[3]);
            v[4] = (short)f2bf(x1[0]); v[5] = (short)f2bf(x1[1]);
            v[6] = (short)f2bf(x1[2]); v[7] = (short)f2bf(x1[3]);
            bfr[ct] = v;
        }
        #pragma unroll
        for (int rt = 0; rt < 2; ++rt) {
            int row = row0 + rt * 16 + n16;
            short8 a = *(const short8*)(We + row * IN_DIM + k);
            #pragma unroll
            for (int ct = 0; ct < 4; ++ct)
                acc[rt][ct] = mfma16(a, bfr[ct], acc[rt][ct]);
        }
    }

    // epilogue: h0 = relu(acc + eb) -> global h + LDS gt
    ushort_t* hob = h_out + ((size_t)(b * TP + PADROWS + t0)) * L;
    #pragma unroll
    for (int rt = 0; rt < 2; ++rt) {
        int i0 = row0 + rt * 16 + q * 4;
        f32x4 eb4 = *(const f32x4*)(eb + i0);
        #pragma unroll
        for (int ct = 0; ct < 4; ++ct) {
            int c = ct * 16 + n16;
            f32x4 h0 = acc[rt][ct] + eb4;
            float v0 = fmaxf(h0[0], 0.f), v1 = fmaxf(h0[1], 0.f);
            float v2 = fmaxf(h0[2], 0.f), v3 = fmaxf(h0[3], 0.f);
            uint_t lo = (uint_t)f2bf(v0) | ((uint_t)f2bf(v1) << 16);
            uint_t hi = (uint_t)f2bf(v2) | ((uint_t)f2bf(v3) << 16);
            *(uint2*)(hob + (size_t)c * L + i0) = make_uint2(lo, hi);
            int byt = (c * 512 + i0 * 2) ^ ((c & 7) << 6);
            *(uint2*)(gt + byt) = make_uint2(lo, hi);
        }
    }
    __syncthreads();

    // skip0 GEMM over gt
    f32x4 accs[2][4];
    #pragma unroll
    for (int rt = 0; rt < 2; ++rt)
        #pragma unroll
        for (int ct = 0; ct < 4; ++ct) accs[rt][ct] = (f32x4){0.f, 0.f, 0.f, 0.f};

    for (int ks = 0; ks < 8; ++ks) {
        const int k = ks * 32 + q * 8;
        short8 bg[4];
        #pragma unroll
        for (int ct = 0; ct < 4; ++ct) {
            int c = ct * 16 + n16;
            bg[ct] = *(const short8*)(gt + ((c * 512 + k * 2) ^ ((c & 7) << 6)));
        }
        #pragma unroll
        for (int rt = 0; rt < 2; ++rt) {
            int row = row0 + rt * 16 + n16;
            short8 a = *(const short8*)(Ws0 + row * L + k);
            #pragma unroll
            for (int ct = 0; ct < 4; ++ct)
                accs[rt][ct] = mfma16(a, bg[ct], accs[rt][ct]);
        }
    }
    float* fob = fin + ((size_t)(b * Tn + t0)) * L;
    #pragma unroll
    for (int rt = 0; rt < 2; ++rt) {
        int i0 = row0 + rt * 16 + q * 4;
        f32x4 sb4 = *(const f32x4*)(sb0 + i0);
        #pragma unroll
        for (int ct = 0; ct < 4; ++ct) {
            int c = ct * 16 + n16;
            *(f32x4*)(fob + (size_t)c * L + i0) = accs[rt][ct] + sb4;  // store (first write)
        }
    }
}

// ---------------------------------------------------------------------------
// one WaveNet layer
// ---------------------------------------------------------------------------
__global__ __launch_bounds__(512, 1) void layer_kernel(
    const ushort_t* __restrict__ h_in, ushort_t* __restrict__ h_out,
    float* __restrict__ fin,
    const ushort_t* __restrict__ Wf, const ushort_t* __restrict__ Wg,
    const ushort_t* __restrict__ Wr, const ushort_t* __restrict__ Ws,
    const float* __restrict__ fb_, const float* __restrict__ gb_,
    const float* __restrict__ rb_, const float* __restrict__ sb_,
    int d)
{
    __shared__ __align__(16) char hh[64 * 1024];  // [64 cols][512 ch] bf16, swz ((c&15)<<6)
    __shared__ __align__(16) char gt[32 * 1024];  // [64 cols][256 ch] bf16, swz ((c&7)<<6)

    const int tid = threadIdx.x;
    const int w = tid >> 6;
    const int ln = tid & 63;
    const int q = ln >> 4;
    const int n16 = ln & 15;
    const int blk = blockIdx.x;
    const int b = blk >> 6;
    const int t0 = (blk & 63) * COLS;
    const int row0 = w * 32;

    // ---- stage hh: row c = [h[t0+c][0..255] | h[t0+c-d][0..255]], source pre-swizzled
    const ushort_t* hbase = h_in + ((size_t)(b * TP + PADROWS + t0)) * L;
    #pragma unroll
    for (int it = 0; it < 8; ++it) {
        int c = it * 8 + w;                       // wave-uniform row
        int chunk = ln ^ ((c & 15) << 2);         // pre-swizzled logical 16B-chunk
        int sh = (chunk >= 32) ? d : 0;
        const ushort_t* src = hbase + ((long)c - sh) * L + (chunk & 31) * 8;
        gld_lds16(src, hh + c * 1024);
    }
    __syncthreads();

    // ---- phase 1: filt & gate (K=512 concat GEMMs)
    f32x4 accf[2][4], accg[2][4];
    #pragma unroll
    for (int rt = 0; rt < 2; ++rt)
        #pragma unroll
        for (int ct = 0; ct < 4; ++ct) {
            accf[rt][ct] = (f32x4){0.f, 0.f, 0.f, 0.f};
            accg[rt][ct] = (f32x4){0.f, 0.f, 0.f, 0.f};
        }

    for (int ks = 0; ks < 16; ++ks) {
        const int k = ks * 32 + q * 8;
        short8 bfr[4];
        #pragma unroll
        for (int ct = 0; ct < 4; ++ct) {
            int c = ct * 16 + n16;
            bfr[ct] = *(const short8*)(hh + ((c * 1024 + k * 2) ^ ((c & 15) << 6)));
        }
        #pragma unroll
        for (int rt = 0; rt < 2; ++rt) {
            int row = row0 + rt * 16 + n16;
            short8 af = *(const short8*)(Wf + row * 512 + k);
            short8 ag = *(const short8*)(Wg + row * 512 + k);
            #pragma unroll
            for (int ct = 0; ct < 4; ++ct) {
                accf[rt][ct] = mfma16(af, bfr[ct], accf[rt][ct]);
                accg[rt][ct] = mfma16(ag, bfr[ct], accg[rt][ct]);
            }
        }
    }

    // ---- epilogue 1: gated = tanh(f+fb)*sigmoid(g+gb) -> gt (bf16, swizzled)
    #pragma unroll
    for (int rt = 0; rt < 2; ++rt) {
        int i0 = row0 + rt * 16 + q * 4;
        f32x4 fb4 = *(const f32x4*)(fb_ + i0);
        f32x4 gb4 = *(const f32x4*)(gb_ + i0);
        #pragma unroll
        for (int ct = 0; ct < 4; ++ct) {
            int c = ct * 16 + n16;
            uint_t pk[2];
            #pragma unroll
            for (int h2 = 0; h2 < 2; ++h2) {
                float v0 = tanh_fast(accf[rt][ct][h2 * 2] + fb4[h2 * 2]) *
                           sigm_fast(accg[rt][ct][h2 * 2] + gb4[h2 * 2]);
                float v1 = tanh_fast(accf[rt][ct][h2 * 2 + 1] + fb4[h2 * 2 + 1]) *
                           sigm_fast(accg[rt][ct][h2 * 2 + 1] + gb4[h2 * 2 + 1]);
                pk[h2] = (uint_t)f2bf(v0) | ((uint_t)f2bf(v1) << 16);
            }
            int byt = (c * 512 + i0 * 2) ^ ((c & 7) << 6);
            *(uint2*)(gt + byt) = make_uint2(pk[0], pk[1]);
        }
    }
    __syncthreads();

    // ---- phase 2: skip (over gt) & res (over hh unshifted half)
    f32x4 accs[2][4], accr[2][4];
    #pragma unroll
    for (int rt = 0; rt < 2; ++rt)
        #pragma unroll
        for (int ct = 0; ct < 4; ++ct) {
            accs[rt][ct] = (f32x4){0.f, 0.f, 0.f, 0.f};
            accr[rt][ct] = (f32x4){0.f, 0.f, 0.f, 0.f};
        }

    for (int ks = 0; ks < 8; ++ks) {
        const int k = ks * 32 + q * 8;
        short8 bg[4], bh[4];
        #pragma unroll
        for (int ct = 0; ct < 4; ++ct) {
            int c = ct * 16 + n16;
            bg[ct] = *(const short8*)(gt + ((c * 512 + k * 2) ^ ((c & 7) << 6)));
            bh[ct] = *(const short8*)(hh + ((c * 1024 + k * 2) ^ ((c & 15) << 6)));
        }
        #pragma unroll
        for (int rt = 0; rt < 2; ++rt) {
            int row = row0 + rt * 16 + n16;
            short8 as_ = *(const short8*)(Ws + row * L + k);
            short8 ar_ = *(const short8*)(Wr + row * L + k);
            #pragma unroll
            for (int ct = 0; ct < 4; ++ct) {
                accs[rt][ct] = mfma16(as_, bg[ct], accs[rt][ct]);
                accr[rt][ct] = mfma16(ar_, bh[ct], accr[rt][ct]);
            }
        }
    }

    // ---- epilogue 2: h' = skip+res (bf16), final += skip (fp32 RMW)
    ushort_t* hob = h_out + ((size_t)(b * TP + PADROWS + t0)) * L;
    float* fob = fin + ((size_t)(b * Tn + t0)) * L;
    #pragma unroll
    for (int rt = 0; rt < 2; ++rt) {
        int i0 = row0 + rt * 16 + q * 4;
        f32x4 sb4 = *(const f32x4*)(sb_ + i0);
        f32x4 rb4 = *(const f32x4*)(rb_ + i0);
        #pragma unroll
        for (int ct = 0; ct < 4; ++ct) {
            int c = ct * 16 + n16;
            f32x4 sk = accs[rt][ct] + sb4;
            f32x4 hn = sk + accr[rt][ct] + rb4;
            uint_t lo = (uint_t)f2bf(hn[0]) | ((uint_t)f2bf(hn[1]) << 16);
            uint_t hi = (uint_t)f2bf(hn[2]) | ((uint_t)f2bf(hn[3]) << 16);
            *(uint2*)(hob + (size_t)c * L + i0) = make_uint2(lo, hi);
            f32x4* fp = (f32x4*)(fob + (size_t)c * L + i0);
            *fp = *fp + sk;
        }
    }
}

// ---------------------------------------------------------------------------
// head: relu->fin1->relu->fin2->out_w->tanh
// ---------------------------------------------------------------------------
__global__ __launch_bounds__(512, 1) void final_kernel(
    const float* __restrict__ fin,
    const ushort_t* __restrict__ W1, const float* __restrict__ b1,
    const ushort_t* __restrict__ W2, const float* __restrict__ b2,
    const ushort_t* __restrict__ Wo, const float* __restrict__ ob,
    float* __restrict__ out)
{
    __shared__ __align__(16) char s1[32 * 1024];
    __shared__ __align__(16) char s2[32 * 1024];

    const int tid = threadIdx.x;
    const int w = tid >> 6;
    const int ln = tid & 63;
    const int q = ln >> 4;
    const int n16 = ln & 15;
    const int blk = blockIdx.x;
    const int b = blk >> 6;
    const int t0 = (blk & 63) * COLS;
    const int row0 = w * 32;

    // stage s1 = bf16(relu(final))
    {
        int c = tid & 63;
        int kg = tid >> 6;
        const float* fp = fin + ((size_t)(b * Tn + t0 + c)) * L + kg * 32;
        #pragma unroll
        for (int j = 0; j < 8; ++j) {
            f32x4 v = *(const f32x4*)(fp + j * 4);
            uint_t lo = (uint_t)f2bf(fmaxf(v[0], 0.f)) | ((uint_t)f2bf(fmaxf(v[1], 0.f)) << 16);
            uint_t hi = (uint_t)f2bf(fmaxf(v[2], 0.f)) | ((uint_t)f2bf(fmaxf(v[3], 0.f)) << 16);
            int kk = kg * 32 + j * 4;
            *(uint2*)(s1 + ((c * 512 + kk * 2) ^ ((c & 7) << 6))) = make_uint2(lo, hi);
        }
    }
    __syncthreads();

    // GEMM1: z1 = W1 @ s1; relu -> s2
    f32x4 acc[2][4];
    #pragma unroll
    for (int rt = 0; rt < 2; ++rt)
        #pragma unroll
        for (int ct = 0; ct < 4; ++ct) acc[rt][ct] = (f32x4){0.f, 0.f, 0.f, 0.f};
    for (int ks = 0; ks < 8; ++ks) {
        const int k = ks * 32 + q * 8;
        short8 bfr[4];
        #pragma unroll
        for (int ct = 0; ct < 4; ++ct) {
            int c = ct * 16 + n16;
            bfr[ct] = *(const short8*)(s1 + ((c * 512 + k * 2) ^ ((c & 7) << 6)));
        }
        #pragma unroll
        for (int rt = 0; rt < 2; ++rt) {
            int row = row0 + rt * 16 + n16;
            short8 a = *(const short8*)(W1 + row * L + k);
            #pragma unroll
            for (int ct = 0; ct < 4; ++ct) acc[rt][ct] = mfma16(a, bfr[ct], acc[rt][ct]);
        }
    }
    #pragma unroll
    for (int rt = 0; rt < 2; ++rt) {
        int i0 = row0 + rt * 16 + q * 4;
        f32x4 bb = *(const f32x4*)(b1 + i0);
        #pragma unroll
        for (int ct = 0; ct < 4; ++ct) {
            int c = ct * 16 + n16;
            f32x4 z = acc[rt][ct] + bb;
            uint_t lo = (uint_t)f2bf(fmaxf(z[0], 0.f)) | ((uint_t)f2bf(fmaxf(z[1], 0.f)) << 16);
            uint_t hi = (uint_t)f2bf(fmaxf(z[2], 0.f)) | ((uint_t)f2bf(fmaxf(z[3], 0.f)) << 16);
            *(uint2*)(s2 + ((c * 512 + i0 * 2) ^ ((c & 7) << 6))) = make_uint2(lo, hi);
        }
    }
    __syncthreads();

    // GEMM2: z2 = W2 @ s2 (no relu) -> s1
    #pragma unroll
    for (int rt = 0; rt < 2; ++rt)
        #pragma unroll
        for (int ct = 0; ct < 4; ++ct) acc[rt][ct] = (f32x4){0.f, 0.f, 0.f, 0.f};
    for (int ks = 0; ks < 8; ++ks) {
        const int k = ks * 32 + q * 8;
        short8 bfr[4];
        #pragma unroll
        for (int ct = 0; ct < 4; ++ct) {
            int c = ct * 16 + n16;
            bfr[ct] = *(const short8*)(s2 + ((c * 512 + k * 2) ^ ((c & 7) << 6)));
        }
        #pragma unroll
        for (int rt = 0; rt < 2; ++rt) {
            int row = row0 + rt * 16 + n16;
            short8 a = *(const short8*)(W2 + row * L + k);
            #pragma unroll
            for (int ct = 0; ct < 4; ++ct) acc[rt][ct] = mfma16(a, bfr[ct], acc[rt][ct]);
        }
    }
    #pragma unroll
    for (int rt = 0; rt < 2; ++rt) {
        int i0 = row0 + rt * 16 + q * 4;
        f32x4 bb = *(const f32x4*)(b2 + i0);
        #pragma unroll
        for (int ct = 0; ct < 4; ++ct) {
            int c = ct * 16 + n16;
            f32x4 z = acc[rt][ct] + bb;
            uint_t lo = (uint_t)f2bf(z[0]) | ((uint_t)f2bf(z[1]) << 16);
            uint_t hi = (uint_t)f2bf(z[2]) | ((uint_t)f2bf(z[3]) << 16);
            *(uint2*)(s1 + ((c * 512 + i0 * 2) ^ ((c & 7) << 6))) = make_uint2(lo, hi);
        }
    }
    __syncthreads();

    // GEMM3: out = tanh(Wo @ z2 + ob)  (M=64, waves 0..3)
    if (w < 4) {
        f32x4 acc3[4];
        #pragma unroll
        for (int ct = 0; ct < 4; ++ct) acc3[ct] = (f32x4){0.f, 0.f, 0.f, 0.f};
        for (int ks = 0; ks < 8; ++ks) {
            const int k = ks * 32 + q * 8;
            short8 bfr[4];
            #pragma unroll
            for (int ct = 0; ct < 4; ++ct) {
                int c = ct * 16 + n16;
                bfr[ct] = *(const short8*)(s1 + ((c * 512 + k * 2) ^ ((c & 7) << 6)));
            }
            short8 a = *(const short8*)(Wo + (w * 16 + n16) * L + k);
            #pragma unroll
            for (int ct = 0; ct < 4; ++ct) acc3[ct] = mfma16(a, bfr[ct], acc3[ct]);
        }
        int o0 = w * 16 + q * 4;
        f32x4 ob4 = *(const f32x4*)(ob + o0);
        float* obase = out + ((size_t)(b * Tn + t0)) * 64;
        #pragma unroll
        for (int ct = 0; ct < 4; ++ct) {
            int c = ct * 16 + n16;
            f32x4 v;
            #pragma unroll
            for (int j = 0; j < 4; ++j) v[j] = tanh_fast(acc3[ct][j] + ob4[j]);
            *(f32x4*)(obase + (size_t)c * 64 + o0) = v;
        }
    }
}

// ---------------------------------------------------------------------------
extern "C" void kernel_launch(void* const* d_in, const int* in_sizes, int n_in,
                              void* d_out, int out_size, void* d_ws, size_t ws_size,
                              hipStream_t stream)
{
    (void)in_sizes; (void)n_in; (void)out_size; (void)ws_size;
    const float* x      = (const float*)d_in[0];
    const float* emb_w  = (const float*)d_in[1];
    const float* emb_b  = (const float*)d_in[2];
    const float* filt_w = (const float*)d_in[3];
    const float* filt_b = (const float*)d_in[4];
    const float* gate_w = (const float*)d_in[5];
    const float* gate_b = (const float*)d_in[6];
    const float* res_w  = (const float*)d_in[7];
    const float* res_b  = (const float*)d_in[8];
    const float* skip_w = (const float*)d_in[9];
    const float* skip_b = (const float*)d_in[10];
    const float* fin1_w = (const float*)d_in[11];
    const float* fin1_b = (const float*)d_in[12];
    const float* fin2_w = (const float*)d_in[13];
    const float* fin2_b = (const float*)d_in[14];
    const float* out_w  = (const float*)d_in[15];
    const float* out_b  = (const float*)d_in[16];

    char* ws = (char*)d_ws;
    size_t off = 0;
    auto alloc = [&](size_t bytes) -> char* {
        char* p = ws + off;
        off += (bytes + 255) & ~(size_t)255;
        return p;
    };
    ushort_t* h_a = (ushort_t*)alloc((size_t)Bn * TP * L * 2);
    ushort_t* h_b = (ushort_t*)alloc((size_t)Bn * TP * L * 2);
    float*    fin = (float*)   alloc((size_t)Bn * Tn * L * 4);
    ushort_t* Wf  = (ushort_t*)alloc((size_t)NL * L * 2 * L * 2);
    ushort_t* Wg  = (ushort_t*)alloc((size_t)NL * L * 2 * L * 2);
    ushort_t* Wr  = (ushort_t*)alloc((size_t)NL * L * L * 2);
    ushort_t* Ws_ = (ushort_t*)alloc((size_t)(NL + 1) * L * L * 2);
    ushort_t* We  = (ushort_t*)alloc((size_t)L * IN_DIM * 2);
    ushort_t* W1  = (ushort_t*)alloc((size_t)L * L * 2);
    ushort_t* W2  = (ushort_t*)alloc((size_t)L * L * 2);
    ushort_t* Wo  = (ushort_t*)alloc((size_t)64 * L * 2);

    prep_kernel<<<512, 256, 0, stream>>>(filt_w, gate_w, res_w, skip_w, emb_w,
        fin1_w, fin2_w, out_w, Wf, Wg, Wr, Ws_, We, W1, W2, Wo, h_a, h_b);

    emb_kernel<<<1024, 512, 0, stream>>>(x, We, emb_b, Ws_, skip_b, h_a, fin);

    ushort_t* hin = h_a;
    ushort_t* hout = h_b;
    for (int i = 0; i < NL; ++i) {
        layer_kernel<<<1024, 512, 0, stream>>>(hin, hout, fin,
            Wf + (size_t)i * L * 2 * L, Wg + (size_t)i * L * 2 * L,
            Wr + (size_t)i * L * L, Ws_ + (size_t)(i + 1) * L * L,
            filt_b + i * L, gate_b + i * L, res_b + i * L, skip_b + (i + 1) * L,
            1 << i);
        ushort_t* t = hin; hin = hout; hout = t;
    }

    final_kernel<<<1024, 512, 0, stream>>>(fin, W1, fin1_b, W2, fin2_b,
        Wo, out_b, (float*)d_out);
}